// Round 4
// baseline (314.794 us; speedup 1.0000x reference)
//
#include <hip/hip_runtime.h>

#define NUM_GRAPHS 512
#define N_NODES 100000
#define N_EDGES 1600000
#define D_NODE 128
#define D_EDGE 32
#define D_OUT 64

#define NB_EDGE 512        // one 64KB LDS histogram per block; exactly 2 blocks/CU
#define EB_THREADS 1024    // 16 waves/block -> 32 waves/CU
#define HIST (NUM_GRAPHS * D_EDGE)   // 16384 floats = 64 KB

// ---------------- kernel 0: eg[e] = batch[col[e]] (streaming, int4) -------------------
__global__ __launch_bounds__(256) void eg_kernel(const int* __restrict__ col,
                                                 const int* __restrict__ batch,
                                                 int* __restrict__ eg) {
    const int i = (blockIdx.x * 256 + threadIdx.x) * 4;
    if (i + 3 < N_EDGES) {
        int4 c = *reinterpret_cast<const int4*>(col + i);
        int g0 = batch[c.x];
        int g1 = batch[c.y];
        int g2 = batch[c.z];
        int g3 = batch[c.w];
        *reinterpret_cast<int4*>(eg + i) = make_int4(g0, g1, g2, g3);
    }
}

// ---------------- kernel 1: node aggregate (batch sorted -> binary search, float4) ----
__global__ __launch_bounds__(512) void node_agg_kernel(const float* __restrict__ x,
                                                       const int* __restrict__ batch,
                                                       float* __restrict__ node_agg) {
    const int g = blockIdx.x;
    int l = 0, r = N_NODES;
    while (l < r) { int m = (l + r) >> 1; if (batch[m] < g) l = m + 1; else r = m; }
    const int lo = l;
    r = N_NODES;
    while (l < r) { int m = (l + r) >> 1; if (batch[m] < g + 1) l = m + 1; else r = m; }
    const int hi = l;

    const int t = threadIdx.x;
    const int d4 = t & 31;   // float4 column (32 * 4 = 128 floats)
    const int rr = t >> 5;   // 0..15 row phase
    const float4* x4 = reinterpret_cast<const float4*>(x);

    float4 a = make_float4(0.f, 0.f, 0.f, 0.f);
    for (int i = lo + rr; i < hi; i += 16) {
        float4 v = x4[(size_t)i * 32 + d4];
        a.x += v.x; a.y += v.y; a.z += v.z; a.w += v.w;
    }

    __shared__ float4 red[512];
    red[t] = a;
    __syncthreads();
    if (t < 32) {
        float4 s = red[t];
        #pragma unroll
        for (int p = 1; p < 16; ++p) {
            float4 v = red[p * 32 + t];
            s.x += v.x; s.y += v.y; s.z += v.z; s.w += v.w;
        }
        reinterpret_cast<float4*>(node_agg)[g * 32 + t] = s;
    }
}

// ---------------- kernel 2: edge partial histograms (pipelined, relaxed LDS atomics) --
// thread (sub, dq): sub = edge slot (128 per group), dq = float4 column of edge_attr row.
// Grid-stride over superblocks of 4 groups; next superblock's 8 loads are issued BEFORE
// the current superblock's 16 LDS adds (explicit software pipeline), and the LDS adds are
// RELAXED workgroup-scope so they carry no fence that would block load hoisting.
__global__ __launch_bounds__(EB_THREADS, 8) void edge_partial_kernel(
        const float* __restrict__ edge_attr,
        const int* __restrict__ eg,
        float* __restrict__ part) {
    __shared__ float acc[HIST];   // 64 KB
    const int t = threadIdx.x;
    float4* acc4 = reinterpret_cast<float4*>(acc);
    for (int i = t; i < HIST / 4; i += EB_THREADS) acc4[i] = make_float4(0.f, 0.f, 0.f, 0.f);
    __syncthreads();

    const int sub = t >> 3;            // 0..127
    const int dq  = t & 7;             // 0..7
    const int EPG = 128;               // edges per group (block-iteration)
    const int NSB = N_EDGES / (EPG * 4);   // 3125 superblocks of 4 groups; exact
    const float4* ea4 = reinterpret_cast<const float4*>(edge_attr);

    int sb = blockIdx.x;
    int g0 = 0, g1 = 0, g2 = 0, g3 = 0;
    float4 v0 = {}, v1 = {}, v2 = {}, v3 = {};

    if (sb < NSB) {
        const int e0 = (sb * 4 + 0) * EPG + sub;
        g0 = eg[e0]; g1 = eg[e0 + EPG]; g2 = eg[e0 + 2 * EPG]; g3 = eg[e0 + 3 * EPG];
        v0 = ea4[(size_t)e0 * 8 + dq];
        v1 = ea4[(size_t)(e0 + EPG) * 8 + dq];
        v2 = ea4[(size_t)(e0 + 2 * EPG) * 8 + dq];
        v3 = ea4[(size_t)(e0 + 3 * EPG) * 8 + dq];
    }

    while (sb < NSB) {
        const int nsb = sb + (int)gridDim.x;
        // stash current into locals
        const int cg0 = g0, cg1 = g1, cg2 = g2, cg3 = g3;
        const float4 cv0 = v0, cv1 = v1, cv2 = v2, cv3 = v3;
        // issue next superblock's loads FIRST
        if (nsb < NSB) {
            const int e0 = (nsb * 4 + 0) * EPG + sub;
            g0 = eg[e0]; g1 = eg[e0 + EPG]; g2 = eg[e0 + 2 * EPG]; g3 = eg[e0 + 3 * EPG];
            v0 = ea4[(size_t)e0 * 8 + dq];
            v1 = ea4[(size_t)(e0 + EPG) * 8 + dq];
            v2 = ea4[(size_t)(e0 + 2 * EPG) * 8 + dq];
            v3 = ea4[(size_t)(e0 + 3 * EPG) * 8 + dq];
        }
        // relaxed workgroup-scope LDS adds (no fences -> loads above stay in flight)
        const int b0 = cg0 * D_EDGE + dq * 4;
        const int b1 = cg1 * D_EDGE + dq * 4;
        const int b2 = cg2 * D_EDGE + dq * 4;
        const int b3 = cg3 * D_EDGE + dq * 4;
        __hip_atomic_fetch_add(&acc[b0 + 0], cv0.x, __ATOMIC_RELAXED, __HIP_MEMORY_SCOPE_WORKGROUP);
        __hip_atomic_fetch_add(&acc[b0 + 1], cv0.y, __ATOMIC_RELAXED, __HIP_MEMORY_SCOPE_WORKGROUP);
        __hip_atomic_fetch_add(&acc[b0 + 2], cv0.z, __ATOMIC_RELAXED, __HIP_MEMORY_SCOPE_WORKGROUP);
        __hip_atomic_fetch_add(&acc[b0 + 3], cv0.w, __ATOMIC_RELAXED, __HIP_MEMORY_SCOPE_WORKGROUP);
        __hip_atomic_fetch_add(&acc[b1 + 0], cv1.x, __ATOMIC_RELAXED, __HIP_MEMORY_SCOPE_WORKGROUP);
        __hip_atomic_fetch_add(&acc[b1 + 1], cv1.y, __ATOMIC_RELAXED, __HIP_MEMORY_SCOPE_WORKGROUP);
        __hip_atomic_fetch_add(&acc[b1 + 2], cv1.z, __ATOMIC_RELAXED, __HIP_MEMORY_SCOPE_WORKGROUP);
        __hip_atomic_fetch_add(&acc[b1 + 3], cv1.w, __ATOMIC_RELAXED, __HIP_MEMORY_SCOPE_WORKGROUP);
        __hip_atomic_fetch_add(&acc[b2 + 0], cv2.x, __ATOMIC_RELAXED, __HIP_MEMORY_SCOPE_WORKGROUP);
        __hip_atomic_fetch_add(&acc[b2 + 1], cv2.y, __ATOMIC_RELAXED, __HIP_MEMORY_SCOPE_WORKGROUP);
        __hip_atomic_fetch_add(&acc[b2 + 2], cv2.z, __ATOMIC_RELAXED, __HIP_MEMORY_SCOPE_WORKGROUP);
        __hip_atomic_fetch_add(&acc[b2 + 3], cv2.w, __ATOMIC_RELAXED, __HIP_MEMORY_SCOPE_WORKGROUP);
        __hip_atomic_fetch_add(&acc[b3 + 0], cv3.x, __ATOMIC_RELAXED, __HIP_MEMORY_SCOPE_WORKGROUP);
        __hip_atomic_fetch_add(&acc[b3 + 1], cv3.y, __ATOMIC_RELAXED, __HIP_MEMORY_SCOPE_WORKGROUP);
        __hip_atomic_fetch_add(&acc[b3 + 2], cv3.z, __ATOMIC_RELAXED, __HIP_MEMORY_SCOPE_WORKGROUP);
        __hip_atomic_fetch_add(&acc[b3 + 3], cv3.w, __ATOMIC_RELAXED, __HIP_MEMORY_SCOPE_WORKGROUP);
        sb = nsb;
    }
    __syncthreads();

    float4* dst = reinterpret_cast<float4*>(part + (size_t)blockIdx.x * HIST);
    for (int i = t; i < HIST / 4; i += EB_THREADS) dst[i] = acc4[i];
}

// ---------------- kernel 3: reduce partials + tiny GEMM -------------------------------
__global__ __launch_bounds__(256) void reduce_gemm_kernel(
        const float* __restrict__ part,
        const float* __restrict__ node_agg,
        const float* __restrict__ W,
        const float* __restrict__ b,
        float* __restrict__ out) {
    const int g = blockIdx.x;
    const int t = threadIdx.x;
    __shared__ float eacc[8][D_EDGE];
    __shared__ float e_final[D_EDGE];
    __shared__ float n_lds[D_NODE];

    const int d = t & 31;
    const int c = t >> 5;                        // 0..7
    float s = 0.f;
    const int PPC = NB_EDGE / 8;                 // 64 partials per chunk
    #pragma unroll 8
    for (int q = 0; q < PPC; ++q) {
        const int p = c * PPC + q;
        s += part[(size_t)p * HIST + g * D_EDGE + d];
    }
    eacc[c][d] = s;
    if (t < D_NODE) n_lds[t] = node_agg[g * D_NODE + t];
    __syncthreads();

    if (t < D_EDGE) {
        float v = 0.f;
        #pragma unroll
        for (int cc = 0; cc < 8; ++cc) v += eacc[cc][t];
        e_final[t] = v;
    }
    __syncthreads();

    if (t < D_OUT) {
        float o = b[t];
        #pragma unroll 8
        for (int k = 0; k < D_NODE; ++k) o += n_lds[k] * W[k * D_OUT + t];
        #pragma unroll 8
        for (int k = 0; k < D_EDGE; ++k) o += e_final[k] * W[(D_NODE + k) * D_OUT + t];
        out[g * D_OUT + t] = o;
    }
}

extern "C" void kernel_launch(void* const* d_in, const int* in_sizes, int n_in,
                              void* d_out, int out_size, void* d_ws, size_t ws_size,
                              hipStream_t stream) {
    const float* x          = (const float*)d_in[0];
    const int*   edge_index = (const int*)d_in[1];
    const float* edge_attr  = (const float*)d_in[2];
    // d_in[3] = u, unused by the reference output
    const int*   batch      = (const int*)d_in[4];
    const float* W          = (const float*)d_in[5];
    const float* b          = (const float*)d_in[6];
    float* out = (float*)d_out;

    const int* col = edge_index + N_EDGES;   // row 1 of edge_index

    // workspace layout
    float* node_agg = (float*)d_ws;                                    // 256 KB
    float* part     = node_agg + (size_t)NUM_GRAPHS * D_NODE;          // 512*64KB = 32 MB
    int*   eg       = (int*)(part + (size_t)NB_EDGE * HIST);           // 6.4 MB

    const int eg_blocks = (N_EDGES / 4 + 255) / 256;                   // 1563
    eg_kernel<<<eg_blocks, 256, 0, stream>>>(col, batch, eg);
    node_agg_kernel<<<NUM_GRAPHS, 512, 0, stream>>>(x, batch, node_agg);
    edge_partial_kernel<<<NB_EDGE, EB_THREADS, 0, stream>>>(edge_attr, eg, part);
    reduce_gemm_kernel<<<NUM_GRAPHS, 256, 0, stream>>>(part, node_agg, W, b, out);
}

// Round 5
// 308.936 us; speedup vs baseline: 1.0190x; 1.0190x over previous
//
#include <hip/hip_runtime.h>

#define NUM_GRAPHS 512
#define N_NODES 100000
#define N_EDGES 1600000
#define D_NODE 128
#define D_EDGE 32
#define D_OUT 64

#define NB_EDGE 512        // one LDS histogram per block; exactly 2 blocks/CU
#define EB_THREADS 1024    // 16 waves/block -> 32 waves/CU
#define HSTRIDE 33         // padded row stride: bank = (g + d) % 32 -> conflict-free atomics
#define HIST_P (NUM_GRAPHS * HSTRIDE)   // 16896 floats = 67.6 KB
#define HIST   (NUM_GRAPHS * D_EDGE)    // dense 16384 floats = 64 KB (part buffer)

// ---------------- kernel 0: eg[e] = batch[col[e]] (streaming, int4) -------------------
__global__ __launch_bounds__(256) void eg_kernel(const int* __restrict__ col,
                                                 const int* __restrict__ batch,
                                                 int* __restrict__ eg) {
    const int i = (blockIdx.x * 256 + threadIdx.x) * 4;
    if (i + 3 < N_EDGES) {
        int4 c = *reinterpret_cast<const int4*>(col + i);
        int g0 = batch[c.x];
        int g1 = batch[c.y];
        int g2 = batch[c.z];
        int g3 = batch[c.w];
        *reinterpret_cast<int4*>(eg + i) = make_int4(g0, g1, g2, g3);
    }
}

// ---------------- kernel 1: node aggregate (batch sorted -> binary search, float4) ----
__global__ __launch_bounds__(512) void node_agg_kernel(const float* __restrict__ x,
                                                       const int* __restrict__ batch,
                                                       float* __restrict__ node_agg) {
    const int g = blockIdx.x;
    int l = 0, r = N_NODES;
    while (l < r) { int m = (l + r) >> 1; if (batch[m] < g) l = m + 1; else r = m; }
    const int lo = l;
    r = N_NODES;
    while (l < r) { int m = (l + r) >> 1; if (batch[m] < g + 1) l = m + 1; else r = m; }
    const int hi = l;

    const int t = threadIdx.x;
    const int d4 = t & 31;   // float4 column (32 * 4 = 128 floats)
    const int rr = t >> 5;   // 0..15 row phase
    const float4* x4 = reinterpret_cast<const float4*>(x);

    float4 a = make_float4(0.f, 0.f, 0.f, 0.f);
    for (int i = lo + rr; i < hi; i += 16) {
        float4 v = x4[(size_t)i * 32 + d4];
        a.x += v.x; a.y += v.y; a.z += v.z; a.w += v.w;
    }

    __shared__ float4 red[512];
    red[t] = a;
    __syncthreads();
    if (t < 32) {
        float4 s = red[t];
        #pragma unroll
        for (int p = 1; p < 16; ++p) {
            float4 v = red[p * 32 + t];
            s.x += v.x; s.y += v.y; s.z += v.z; s.w += v.w;
        }
        reinterpret_cast<float4*>(node_agg)[g * 32 + t] = s;
    }
}

// ---------------- kernel 2: edge partial histograms (stride-33 LDS, conflict-free) ----
// thread (sub, dq): sub = edge slot (128/block-iter), dq = float4 column of edge_attr row.
// Histogram row stride 33: LDS bank = (g*33 + d) % 32 = (g + d) % 32, so the 64 lanes of
// each ds_add spread over ~all 32 banks instead of 8 (stride 32 put g*32 ≡ 0 mod 32).
__global__ __launch_bounds__(EB_THREADS, 8) void edge_partial_kernel(
        const float* __restrict__ edge_attr,
        const int* __restrict__ eg,
        float* __restrict__ part) {
    __shared__ float acc[HIST_P];   // 67.6 KB
    const int t = threadIdx.x;
    for (int i = t; i < HIST_P; i += EB_THREADS) acc[i] = 0.f;
    __syncthreads();

    const int sub = t >> 3;            // 0..127
    const int dq  = t & 7;             // 0..7
    const int EPG = EB_THREADS / 8;    // 128 edges per block-iteration
    const int ngrp = N_EDGES / EPG;    // 12500 exactly
    const int chunk = (ngrp + NB_EDGE - 1) / NB_EDGE;   // 25 (exact: 12500/512 -> 24.4 -> 25)
    const int gbeg = blockIdx.x * chunk;
    const int gend = min(ngrp, gbeg + chunk);
    const float4* ea4 = reinterpret_cast<const float4*>(edge_attr);

    int grp = gbeg;
    for (; grp + 4 <= gend; grp += 4) {
        const int e0 = (grp + 0) * EPG + sub;
        const int e1 = e0 + EPG, e2 = e1 + EPG, e3 = e2 + EPG;
        const int g0 = eg[e0], g1 = eg[e1], g2 = eg[e2], g3 = eg[e3];
        const float4 v0 = ea4[(size_t)e0 * 8 + dq];
        const float4 v1 = ea4[(size_t)e1 * 8 + dq];
        const float4 v2 = ea4[(size_t)e2 * 8 + dq];
        const float4 v3 = ea4[(size_t)e3 * 8 + dq];
        const int b0 = g0 * HSTRIDE + dq * 4;
        const int b1 = g1 * HSTRIDE + dq * 4;
        const int b2 = g2 * HSTRIDE + dq * 4;
        const int b3 = g3 * HSTRIDE + dq * 4;
        atomicAdd(&acc[b0 + 0], v0.x); atomicAdd(&acc[b0 + 1], v0.y);
        atomicAdd(&acc[b0 + 2], v0.z); atomicAdd(&acc[b0 + 3], v0.w);
        atomicAdd(&acc[b1 + 0], v1.x); atomicAdd(&acc[b1 + 1], v1.y);
        atomicAdd(&acc[b1 + 2], v1.z); atomicAdd(&acc[b1 + 3], v1.w);
        atomicAdd(&acc[b2 + 0], v2.x); atomicAdd(&acc[b2 + 1], v2.y);
        atomicAdd(&acc[b2 + 2], v2.z); atomicAdd(&acc[b2 + 3], v2.w);
        atomicAdd(&acc[b3 + 0], v3.x); atomicAdd(&acc[b3 + 1], v3.y);
        atomicAdd(&acc[b3 + 2], v3.z); atomicAdd(&acc[b3 + 3], v3.w);
    }
    for (; grp < gend; ++grp) {
        const int e = grp * EPG + sub;
        const int g = eg[e];
        const float4 v = ea4[(size_t)e * 8 + dq];
        const int b = g * HSTRIDE + dq * 4;
        atomicAdd(&acc[b + 0], v.x); atomicAdd(&acc[b + 1], v.y);
        atomicAdd(&acc[b + 2], v.z); atomicAdd(&acc[b + 3], v.w);
    }
    __syncthreads();

    // drain: convert strided LDS -> dense global partial (stride 32)
    // thread t: g = t>>1, half = t&1 -> copies 16 floats as 4 float4 stores
    {
        const int g = t >> 1;
        const int half = (t & 1) * 16;
        const float* src = acc + g * HSTRIDE + half;
        float4* dst = reinterpret_cast<float4*>(part + (size_t)blockIdx.x * HIST + g * D_EDGE + half);
        #pragma unroll
        for (int q = 0; q < 4; ++q)
            dst[q] = make_float4(src[q * 4 + 0], src[q * 4 + 1], src[q * 4 + 2], src[q * 4 + 3]);
    }
}

// ---------------- kernel 3: reduce partials + tiny GEMM -------------------------------
__global__ __launch_bounds__(256) void reduce_gemm_kernel(
        const float* __restrict__ part,
        const float* __restrict__ node_agg,
        const float* __restrict__ W,
        const float* __restrict__ b,
        float* __restrict__ out) {
    const int g = blockIdx.x;
    const int t = threadIdx.x;
    __shared__ float eacc[8][D_EDGE];
    __shared__ float e_final[D_EDGE];
    __shared__ float n_lds[D_NODE];

    const int d = t & 31;
    const int c = t >> 5;                        // 0..7
    float s = 0.f;
    const int PPC = NB_EDGE / 8;                 // 64 partials per chunk
    #pragma unroll 8
    for (int q = 0; q < PPC; ++q) {
        const int p = c * PPC + q;
        s += part[(size_t)p * HIST + g * D_EDGE + d];
    }
    eacc[c][d] = s;
    if (t < D_NODE) n_lds[t] = node_agg[g * D_NODE + t];
    __syncthreads();

    if (t < D_EDGE) {
        float v = 0.f;
        #pragma unroll
        for (int cc = 0; cc < 8; ++cc) v += eacc[cc][t];
        e_final[t] = v;
    }
    __syncthreads();

    if (t < D_OUT) {
        float o = b[t];
        #pragma unroll 8
        for (int k = 0; k < D_NODE; ++k) o += n_lds[k] * W[k * D_OUT + t];
        #pragma unroll 8
        for (int k = 0; k < D_EDGE; ++k) o += e_final[k] * W[(D_NODE + k) * D_OUT + t];
        out[g * D_OUT + t] = o;
    }
}

extern "C" void kernel_launch(void* const* d_in, const int* in_sizes, int n_in,
                              void* d_out, int out_size, void* d_ws, size_t ws_size,
                              hipStream_t stream) {
    const float* x          = (const float*)d_in[0];
    const int*   edge_index = (const int*)d_in[1];
    const float* edge_attr  = (const float*)d_in[2];
    // d_in[3] = u, unused by the reference output
    const int*   batch      = (const int*)d_in[4];
    const float* W          = (const float*)d_in[5];
    const float* b          = (const float*)d_in[6];
    float* out = (float*)d_out;

    const int* col = edge_index + N_EDGES;   // row 1 of edge_index

    // workspace layout
    float* node_agg = (float*)d_ws;                                    // 256 KB
    float* part     = node_agg + (size_t)NUM_GRAPHS * D_NODE;          // 512*64KB = 32 MB
    int*   eg       = (int*)(part + (size_t)NB_EDGE * HIST);           // 6.4 MB

    const int eg_blocks = (N_EDGES / 4 + 255) / 256;                   // 1563
    eg_kernel<<<eg_blocks, 256, 0, stream>>>(col, batch, eg);
    node_agg_kernel<<<NUM_GRAPHS, 512, 0, stream>>>(x, batch, node_agg);
    edge_partial_kernel<<<NB_EDGE, EB_THREADS, 0, stream>>>(edge_attr, eg, part);
    reduce_gemm_kernel<<<NUM_GRAPHS, 256, 0, stream>>>(part, node_agg, W, b, out);
}

// Round 6
// 185.433 us; speedup vs baseline: 1.6976x; 1.6660x over previous
//
#include <hip/hip_runtime.h>

#define NUM_GRAPHS 512
#define N_NODES 100000
#define N_EDGES 1600000
#define D_NODE 128
#define D_EDGE 32
#define D_OUT 64

#define NSET 8                      // bucket sets; set = blockIdx&7 ~ XCD under round-robin
#define CAP 768                     // slots per (set,graph) bin; mean 390, sigma ~20 -> 19 sigma margin
#define NBINS (NSET * NUM_GRAPHS)   // 4096

// ---------------- kernel 0: zero the cursors (graph-capture-safe init) ----------------
__global__ __launch_bounds__(256) void zero_kernel(int* __restrict__ cursors) {
    const int t = blockIdx.x * 256 + threadIdx.x;
    if (t < NBINS) cursors[t] = 0;
}

// ---------------- kernel 1: scatter edge ids into per-(set,graph) buckets -------------
// One device atomic per EDGE (1.6M total over 4096 addresses), not per float (51.2M).
__global__ __launch_bounds__(256) void scatter_kernel(const int* __restrict__ col,
                                                      const int* __restrict__ batch,
                                                      int* __restrict__ cursors,
                                                      int* __restrict__ bucket) {
    const int e = blockIdx.x * 256 + threadIdx.x;
    if (e >= N_EDGES) return;
    const int set = blockIdx.x & (NSET - 1);     // blocks round-robin XCDs -> per-XCD bucket region
    const int c = col[e];                        // coalesced
    const int g = batch[c];                      // gather, batch L2/L3-resident (400 KB)
    const int bin = set * NUM_GRAPHS + g;
    const int slot = atomicAdd(&cursors[bin], 1);
    if (slot < CAP) bucket[(size_t)bin * CAP + slot] = e;
}

// ---------------- kernel 2: node aggregate (batch sorted -> binary search, float4) ----
__global__ __launch_bounds__(512) void node_agg_kernel(const float* __restrict__ x,
                                                       const int* __restrict__ batch,
                                                       float* __restrict__ node_agg) {
    const int g = blockIdx.x;
    int l = 0, r = N_NODES;
    while (l < r) { int m = (l + r) >> 1; if (batch[m] < g) l = m + 1; else r = m; }
    const int lo = l;
    r = N_NODES;
    while (l < r) { int m = (l + r) >> 1; if (batch[m] < g + 1) l = m + 1; else r = m; }
    const int hi = l;

    const int t = threadIdx.x;
    const int d4 = t & 31;   // float4 column (32 * 4 = 128 floats)
    const int rr = t >> 5;   // 0..15 row phase
    const float4* x4 = reinterpret_cast<const float4*>(x);

    float4 a = make_float4(0.f, 0.f, 0.f, 0.f);
    for (int i = lo + rr; i < hi; i += 16) {
        float4 v = x4[(size_t)i * 32 + d4];
        a.x += v.x; a.y += v.y; a.z += v.z; a.w += v.w;
    }

    __shared__ float4 red[512];
    red[t] = a;
    __syncthreads();
    if (t < 32) {
        float4 s = red[t];
        #pragma unroll
        for (int p = 1; p < 16; ++p) {
            float4 v = red[p * 32 + t];
            s.x += v.x; s.y += v.y; s.z += v.z; s.w += v.w;
        }
        reinterpret_cast<float4*>(node_agg)[g * 32 + t] = s;
    }
}

// ---------------- kernel 3: gather-sum edges per graph (NO atomics, register acc) -----
// Block g: threads (slot0 = t>>3, dq = t&7). 8 threads share an edge id (broadcast load);
// their 8 float4 reads cover the edge's full 128B row contiguously. Two slots per
// iteration -> 2 independent id->attr chains in flight per lane.
__global__ __launch_bounds__(512) void gather_kernel(const float* __restrict__ edge_attr,
                                                     const int* __restrict__ cursors,
                                                     const int* __restrict__ bucket,
                                                     float* __restrict__ edge_agg) {
    const int g = blockIdx.x;
    const int t = threadIdx.x;
    const int slot0 = t >> 3;      // 0..63
    const int dq = t & 7;          // float4 column
    const float4* ea4 = reinterpret_cast<const float4*>(edge_attr);

    float4 a0 = make_float4(0.f, 0.f, 0.f, 0.f);
    float4 a1 = make_float4(0.f, 0.f, 0.f, 0.f);

    for (int set = 0; set < NSET; ++set) {
        const int bin = set * NUM_GRAPHS + g;
        const int n = min(cursors[bin], CAP);
        const int* brow = bucket + (size_t)bin * CAP;
        for (int base = 0; base < n; base += 128) {
            const int s0 = base + slot0;
            const int s1 = s0 + 64;
            const int id0 = (s0 < n) ? brow[s0] : -1;
            const int id1 = (s1 < n) ? brow[s1] : -1;
            if (id0 >= 0) {
                const float4 v = ea4[(size_t)id0 * 8 + dq];
                a0.x += v.x; a0.y += v.y; a0.z += v.z; a0.w += v.w;
            }
            if (id1 >= 0) {
                const float4 v = ea4[(size_t)id1 * 8 + dq];
                a1.x += v.x; a1.y += v.y; a1.z += v.z; a1.w += v.w;
            }
        }
    }
    a0.x += a1.x; a0.y += a1.y; a0.z += a1.z; a0.w += a1.w;

    __shared__ float4 red[512];
    __shared__ float4 red2[64];
    red[t] = a0;
    __syncthreads();
    if (t < 64) {                    // t = part*8 + dq2
        const int dq2 = t & 7, part = t >> 3;
        float4 s = make_float4(0.f, 0.f, 0.f, 0.f);
        #pragma unroll
        for (int k = 0; k < 8; ++k) {
            const float4 v = red[(part * 8 + k) * 8 + dq2];
            s.x += v.x; s.y += v.y; s.z += v.z; s.w += v.w;
        }
        red2[t] = s;
    }
    __syncthreads();
    if (t < 8) {                     // dq = t
        float4 s = red2[t];
        #pragma unroll
        for (int k = 1; k < 8; ++k) {
            const float4 v = red2[k * 8 + t];
            s.x += v.x; s.y += v.y; s.z += v.z; s.w += v.w;
        }
        reinterpret_cast<float4*>(edge_agg + g * D_EDGE)[t] = s;
    }
}

// ---------------- kernel 4: tiny GEMM: out[g] = [node_agg|edge_agg] @ W + b -----------
__global__ __launch_bounds__(64) void gemm_kernel(const float* __restrict__ node_agg,
                                                  const float* __restrict__ edge_agg,
                                                  const float* __restrict__ W,
                                                  const float* __restrict__ b,
                                                  float* __restrict__ out) {
    const int g = blockIdx.x;
    const int t = threadIdx.x;       // output column
    __shared__ float feat[D_NODE + D_EDGE];
    for (int i = t; i < D_NODE; i += 64) feat[i] = node_agg[g * D_NODE + i];
    if (t < D_EDGE) feat[D_NODE + t] = edge_agg[g * D_EDGE + t];
    __syncthreads();

    float o = b[t];
    #pragma unroll 8
    for (int k = 0; k < D_NODE + D_EDGE; ++k)
        o += feat[k] * W[k * D_OUT + t];     // W L2-hot (41 KB), 256B coalesced per k
    out[g * D_OUT + t] = o;
}

extern "C" void kernel_launch(void* const* d_in, const int* in_sizes, int n_in,
                              void* d_out, int out_size, void* d_ws, size_t ws_size,
                              hipStream_t stream) {
    const float* x          = (const float*)d_in[0];
    const int*   edge_index = (const int*)d_in[1];
    const float* edge_attr  = (const float*)d_in[2];
    // d_in[3] = u, unused by the reference output
    const int*   batch      = (const int*)d_in[4];
    const float* W          = (const float*)d_in[5];
    const float* b          = (const float*)d_in[6];
    float* out = (float*)d_out;

    const int* col = edge_index + N_EDGES;   // row 1 of edge_index

    // workspace layout (~12.9 MB)
    int*   cursors  = (int*)d_ws;                                   // 4096 ints = 16 KB
    int*   bucket   = cursors + NBINS;                              // 4096*768 ints = 12.58 MB
    float* node_agg = (float*)(bucket + (size_t)NBINS * CAP);       // 256 KB
    float* edge_agg = node_agg + NUM_GRAPHS * D_NODE;               // 64 KB

    zero_kernel<<<(NBINS + 255) / 256, 256, 0, stream>>>(cursors);
    scatter_kernel<<<(N_EDGES + 255) / 256, 256, 0, stream>>>(col, batch, cursors, bucket);
    node_agg_kernel<<<NUM_GRAPHS, 512, 0, stream>>>(x, batch, node_agg);
    gather_kernel<<<NUM_GRAPHS, 512, 0, stream>>>(edge_attr, cursors, bucket, edge_agg);
    gemm_kernel<<<NUM_GRAPHS, 64, 0, stream>>>(node_agg, edge_agg, W, b, out);
}